// Round 1
// baseline (4855.502 us; speedup 1.0000x reference)
//
#include <hip/hip_runtime.h>

// GCNStoModel_MultiHead: 2-layer GraphSAGE-GCN + linear head.
// Shapes (fixed by problem): IN=128, HID=256, OUT=256, PHEAD=64
// N0=1048576, E0=2097152, ND0=131072, E1=131072, ND1=8192, task_index=0.
//
// Pipeline:
//   neigh0 = x[:ND0]; deg0 = 1.0                       (init0)
//   neigh0[dst0] += x[src0]; deg0[dst0] += 1           (scatter0, fp32 atomics)
//   h1 = relu((neigh0 * (1/deg0)) @ W1^T + b1)          (gemm, row-scale epilogue)
//   neigh1 = h1[:ND1]; deg1 = 1.0                      (init1)
//   neigh1[dst1] += h1[src1]; deg1[dst1] += 1          (scatter1)
//   h2 = relu((neigh1 * (1/deg1)) @ W2^T + b2)
//   out = h2 @ Wh^T + bh                               (task_index==0)

#define GEMM_BM 64
#define GEMM_BN 64
#define GEMM_BK 32

// ---------------------------------------------------------------------------
// init: neigh[i][:] = src_feat[i][:], deg[i] = 1.0   (K = 4 << LOGQ floats/row)
// one thread per float4; LOGQ = log2(K/4)
template<int LOGQ>
__global__ __launch_bounds__(256) void init_kernel(const float* __restrict__ src_feat,
                                                   float* __restrict__ neigh,
                                                   float* __restrict__ deg, int ND) {
    int gid = blockIdx.x * 256 + threadIdx.x;
    int i = gid >> LOGQ;
    int q = gid & ((1 << LOGQ) - 1);
    if (i >= ND) return;
    size_t off = ((size_t)i << (LOGQ + 2)) + (size_t)q * 4;
    *(float4*)(neigh + off) = *(const float4*)(src_feat + off);
    if (q == 0) deg[i] = 1.0f;
}

// ---------------------------------------------------------------------------
// scatter: for each edge e: neigh[dst[e]][:] += feat[src[e]][:]; deg[dst[e]] += 1
// (1<<LOGQ) threads per edge, one float4 per thread.
template<int LOGQ>
__global__ __launch_bounds__(256) void scatter_kernel(const float* __restrict__ feat,
                                                      const int* __restrict__ src,
                                                      const int* __restrict__ dst,
                                                      float* __restrict__ neigh,
                                                      float* __restrict__ deg, int E) {
    long long gid = (long long)blockIdx.x * 256 + threadIdx.x;
    long long e = gid >> LOGQ;
    int q = (int)(gid & ((1 << LOGQ) - 1));
    if (e >= E) return;
    int s = src[e];
    int d = dst[e];
    const float4 v = *(const float4*)(feat + ((size_t)s << (LOGQ + 2)) + (size_t)q * 4);
    float* o = neigh + ((size_t)d << (LOGQ + 2)) + (size_t)q * 4;
    atomicAdd(o + 0, v.x);
    atomicAdd(o + 1, v.y);
    atomicAdd(o + 2, v.z);
    atomicAdd(o + 3, v.w);
    if (q == 0) atomicAdd(deg + d, 1.0f);
}

// ---------------------------------------------------------------------------
// C[M,N] = act( (A * rowscale) @ W^T + b ), rowscale = 1/deg (optional)
// fp32, BM=BN=64, BK=32, 256 threads, 4x4 register micro-tile per thread.
// M % 64 == 0, N % 64 == 0, K % 32 == 0 (all true for our shapes).
template<bool RELU, bool HAS_RS>
__global__ __launch_bounds__(256) void gemm_kernel(const float* __restrict__ A,    // M x K
                                                   const float* __restrict__ deg,  // M or null
                                                   const float* __restrict__ W,    // N x K
                                                   const float* __restrict__ bias, // N
                                                   float* __restrict__ C,          // M x N
                                                   int M, int N, int K) {
    __shared__ float As[GEMM_BK][GEMM_BM];  // [k][m]
    __shared__ float Ws[GEMM_BK][GEMM_BN];  // [k][n]

    const int t = threadIdx.x;
    const int row0 = blockIdx.x * GEMM_BM;
    const int col0 = blockIdx.y * GEMM_BN;

    const int tm = (t & 15) * 4;   // 4 rows
    const int tn = (t >> 4) * 4;   // 4 cols

    float acc[4][4] = {};

    const int lr = t >> 3;          // 0..31 (row within half-tile)
    const int lk = (t & 7) * 4;     // k-quad offset 0,4,...,28

    for (int k0 = 0; k0 < K; k0 += GEMM_BK) {
        // stage A tile (64x32) — transpose to [k][m]
        #pragma unroll
        for (int pass = 0; pass < 2; ++pass) {
            int r = lr + pass * 32;
            const float4 v = *(const float4*)(A + (size_t)(row0 + r) * K + k0 + lk);
            As[lk + 0][r] = v.x;
            As[lk + 1][r] = v.y;
            As[lk + 2][r] = v.z;
            As[lk + 3][r] = v.w;
        }
        // stage W tile (64x32) — transpose to [k][n]
        #pragma unroll
        for (int pass = 0; pass < 2; ++pass) {
            int n = lr + pass * 32;
            const float4 v = *(const float4*)(W + (size_t)(col0 + n) * K + k0 + lk);
            Ws[lk + 0][n] = v.x;
            Ws[lk + 1][n] = v.y;
            Ws[lk + 2][n] = v.z;
            Ws[lk + 3][n] = v.w;
        }
        __syncthreads();

        #pragma unroll
        for (int k = 0; k < GEMM_BK; ++k) {
            const float4 a = *(const float4*)&As[k][tm];
            const float4 w = *(const float4*)&Ws[k][tn];
            acc[0][0] += a.x * w.x; acc[0][1] += a.x * w.y; acc[0][2] += a.x * w.z; acc[0][3] += a.x * w.w;
            acc[1][0] += a.y * w.x; acc[1][1] += a.y * w.y; acc[1][2] += a.y * w.z; acc[1][3] += a.y * w.w;
            acc[2][0] += a.z * w.x; acc[2][1] += a.z * w.y; acc[2][2] += a.z * w.z; acc[2][3] += a.z * w.w;
            acc[3][0] += a.w * w.x; acc[3][1] += a.w * w.y; acc[3][2] += a.w * w.z; acc[3][3] += a.w * w.w;
        }
        __syncthreads();
    }

    // epilogue: row-scale, bias, relu
    float scl[4];
    #pragma unroll
    for (int i = 0; i < 4; ++i)
        scl[i] = HAS_RS ? (1.0f / deg[row0 + tm + i]) : 1.0f;

    float bb[4];
    #pragma unroll
    for (int j = 0; j < 4; ++j) bb[j] = bias[col0 + tn + j];

    #pragma unroll
    for (int i = 0; i < 4; ++i) {
        float4 v;
        v.x = acc[i][0] * scl[i] + bb[0];
        v.y = acc[i][1] * scl[i] + bb[1];
        v.z = acc[i][2] * scl[i] + bb[2];
        v.w = acc[i][3] * scl[i] + bb[3];
        if (RELU) {
            v.x = fmaxf(v.x, 0.0f); v.y = fmaxf(v.y, 0.0f);
            v.z = fmaxf(v.z, 0.0f); v.w = fmaxf(v.w, 0.0f);
        }
        *(float4*)(C + (size_t)(row0 + tm + i) * N + col0 + tn) = v;
    }
}

// ---------------------------------------------------------------------------
extern "C" void kernel_launch(void* const* d_in, const int* in_sizes, int n_in,
                              void* d_out, int out_size, void* d_ws, size_t ws_size,
                              hipStream_t stream) {
    const float* x   = (const float*)d_in[0];
    const int* src0  = (const int*)d_in[1];
    const int* dst0  = (const int*)d_in[2];
    const int* src1  = (const int*)d_in[3];
    const int* dst1  = (const int*)d_in[4];
    const float* W1  = (const float*)d_in[5];
    const float* b1  = (const float*)d_in[6];
    const float* W2  = (const float*)d_in[7];
    const float* b2  = (const float*)d_in[8];
    const float* Wh  = (const float*)d_in[9];
    const float* bh  = (const float*)d_in[10];

    const int E0 = in_sizes[1];
    const int E1 = in_sizes[3];
    const int IN = 128, HID = 256, OUT = 256, PHEAD = 64;
    const int ND0 = 131072, ND1 = 8192;  // values of n_dst0 / n_dst1 (fixed)

    float* ws = (float*)d_ws;
    float* neigh0 = ws;                          // ND0*IN  = 16,777,216 f
    float* deg0   = neigh0 + (size_t)ND0 * IN;   // ND0     = 131,072 f
    float* h1     = deg0 + ND0;                  // ND0*HID = 33,554,432 f
    // neigh0 region is dead after gemm1 — reuse it for layer-2 buffers
    float* neigh1 = neigh0;                      // ND1*HID = 2,097,152 f
    float* deg1   = neigh1 + (size_t)ND1 * HID;  // ND1
    float* h2     = deg1 + ND1;                  // ND1*OUT = 2,097,152 f
    float* out    = (float*)d_out;               // ND1*PHEAD

    // ---- layer 0 ----
    {
        int T = ND0 * (IN / 4);  // one thread per float4
        init_kernel<5><<<(T + 255) / 256, 256, 0, stream>>>(x, neigh0, deg0, ND0);
    }
    {
        long long T = (long long)E0 * (IN / 4);
        scatter_kernel<5><<<(unsigned)((T + 255) / 256), 256, 0, stream>>>(
            x, src0, dst0, neigh0, deg0, E0);
    }
    {
        dim3 g(ND0 / GEMM_BM, HID / GEMM_BN);
        gemm_kernel<true, true><<<g, 256, 0, stream>>>(neigh0, deg0, W1, b1, h1, ND0, HID, IN);
    }
    // ---- layer 1 ----
    {
        int T = ND1 * (HID / 4);
        init_kernel<6><<<(T + 255) / 256, 256, 0, stream>>>(h1, neigh1, deg1, ND1);
    }
    {
        long long T = (long long)E1 * (HID / 4);
        scatter_kernel<6><<<(unsigned)((T + 255) / 256), 256, 0, stream>>>(
            h1, src1, dst1, neigh1, deg1, E1);
    }
    {
        dim3 g(ND1 / GEMM_BM, OUT / GEMM_BN);
        gemm_kernel<true, true><<<g, 256, 0, stream>>>(neigh1, deg1, W2, b2, h2, ND1, OUT, HID);
    }
    // ---- head (task_index == 0) ----
    {
        dim3 g(ND1 / GEMM_BM, PHEAD / GEMM_BN);
        gemm_kernel<false, false><<<g, 256, 0, stream>>>(h2, nullptr, Wh, bh, out, ND1, PHEAD, OUT);
    }
}

// Round 2
// 1400.868 us; speedup vs baseline: 3.4661x; 3.4661x over previous
//
#include <hip/hip_runtime.h>

// GCNStoModel_MultiHead: 2-layer GraphSAGE-GCN + linear head.
// IN=128, HID=256, OUT=256, PHEAD=64
// N0=1048576, E0=2097152, ND0=131072, E1=131072, ND1=8192, task_index=0.
//
// R1: replaced fp32-atomic scatter (4.4 GB HBM write amplification, 3.6 ms)
// with device-built CSR (hist -> 2-level scan -> fill) + gather aggregation
// (one wave per dst row, row in registers, zero float atomics).

#define GEMM_BM 64
#define GEMM_BN 64
#define GEMM_BK 32

// ---------------------------------------------------------------------------
// CSR build step 1: count[d] = #edges with dst==d   (count pre-zeroed)
__global__ __launch_bounds__(256) void hist_kernel(const int* __restrict__ dst,
                                                   int* __restrict__ count, int E) {
    int e = blockIdx.x * 256 + threadIdx.x;
    if (e >= E) return;
    atomicAdd(&count[dst[e]], 1);
}

// CSR build step 2a: per-block (1024-elem) sums
__global__ __launch_bounds__(256) void block_sum_kernel(const int* __restrict__ count,
                                                        int* __restrict__ bsum) {
    __shared__ int sdata[256];
    int t = threadIdx.x;
    int i = blockIdx.x * 1024 + t * 4;
    int s = count[i] + count[i + 1] + count[i + 2] + count[i + 3];
    sdata[t] = s;
    __syncthreads();
    for (int off = 128; off > 0; off >>= 1) {
        if (t < off) sdata[t] += sdata[t + off];
        __syncthreads();
    }
    if (t == 0) bsum[blockIdx.x] = sdata[0];
}

// CSR build step 2b: exclusive scan of nb block sums (nb <= 256), one block
__global__ __launch_bounds__(256) void scan_small_kernel(const int* __restrict__ bsum,
                                                         int* __restrict__ boff, int nb) {
    __shared__ int sdata[256];
    int t = threadIdx.x;
    int v = (t < nb) ? bsum[t] : 0;
    sdata[t] = v;
    __syncthreads();
    int val = v;
    for (int off = 1; off < 256; off <<= 1) {
        int x = (t >= off) ? sdata[t - off] : 0;
        __syncthreads();
        val += x;
        sdata[t] = val;
        __syncthreads();
    }
    if (t < nb) boff[t] = val - v;  // exclusive
}

// CSR build step 2c: final exclusive scan -> row_start (and cursor copy)
__global__ __launch_bounds__(256) void scan_final_kernel(const int* __restrict__ count,
                                                         const int* __restrict__ boff,
                                                         int* __restrict__ row_start,
                                                         int* __restrict__ cursor) {
    __shared__ int sdata[256];
    int t = threadIdx.x;
    int base_i = blockIdx.x * 1024 + t * 4;
    int c0 = count[base_i], c1 = count[base_i + 1], c2 = count[base_i + 2], c3 = count[base_i + 3];
    int local = c0 + c1 + c2 + c3;
    sdata[t] = local;
    __syncthreads();
    int val = local;
    for (int off = 1; off < 256; off <<= 1) {
        int x = (t >= off) ? sdata[t - off] : 0;
        __syncthreads();
        val += x;
        sdata[t] = val;
        __syncthreads();
    }
    int base = boff[blockIdx.x] + (val - local);  // exclusive prefix
    int r0 = base, r1 = r0 + c0, r2 = r1 + c1, r3 = r2 + c2;
    row_start[base_i] = r0; row_start[base_i + 1] = r1;
    row_start[base_i + 2] = r2; row_start[base_i + 3] = r3;
    cursor[base_i] = r0; cursor[base_i + 1] = r1;
    cursor[base_i + 2] = r2; cursor[base_i + 3] = r3;
}

// CSR build step 3: bucket edges by dst
__global__ __launch_bounds__(256) void fill_kernel(const int* __restrict__ src,
                                                   const int* __restrict__ dst,
                                                   int* __restrict__ cursor,
                                                   int* __restrict__ edge_src, int E) {
    int e = blockIdx.x * 256 + threadIdx.x;
    if (e >= E) return;
    int d = dst[e];
    int p = atomicAdd(&cursor[d], 1);
    edge_src[p] = src[e];
}

// ---------------------------------------------------------------------------
// gather aggregation: one wave per dst row; row held in registers (RF floats
// per lane, K = 64*RF). neigh[d] = selff[d] + sum_{e in row d} feat[src[e]];
// deg[d] = count[d] + 1. No float atomics.
template<int RF> struct VecSel;
template<> struct VecSel<2> { using V = float2; };
template<> struct VecSel<4> { using V = float4; };

template<int RF>
__global__ __launch_bounds__(256) void agg_kernel(const float* __restrict__ feat,
                                                  const float* __restrict__ selff,
                                                  const int* __restrict__ row_start,
                                                  const int* __restrict__ count,
                                                  const int* __restrict__ edge_src,
                                                  float* __restrict__ neigh,
                                                  float* __restrict__ deg, int ND) {
    using V = typename VecSel<RF>::V;
    int w = (blockIdx.x * 256 + threadIdx.x) >> 6;  // wave id == dst row
    int lane = threadIdx.x & 63;
    if (w >= ND) return;
    const int K = 64 * RF;
    size_t lo = (size_t)w * K + (size_t)lane * RF;
    V acc = *(const V*)(selff + lo);
    int rs = row_start[w];
    int cnt = count[w];
    for (int j = 0; j < cnt; ++j) {
        int s = edge_src[rs + j];
        V v = *(const V*)(feat + (size_t)s * K + (size_t)lane * RF);
        acc.x += v.x; acc.y += v.y;
        if constexpr (RF == 4) { acc.z += v.z; acc.w += v.w; }
    }
    *(V*)(neigh + lo) = acc;
    if (lane == 0) deg[w] = (float)(cnt + 1);
}

// ---------------------------------------------------------------------------
// C[M,N] = act( (A * rowscale) @ W^T + b ), fp32, 64x64x32 tiles, 4x4/thread.
template<bool RELU, bool HAS_RS>
__global__ __launch_bounds__(256) void gemm_kernel(const float* __restrict__ A,    // M x K
                                                   const float* __restrict__ deg,  // M or null
                                                   const float* __restrict__ W,    // N x K
                                                   const float* __restrict__ bias, // N
                                                   float* __restrict__ C,          // M x N
                                                   int M, int N, int K) {
    __shared__ float As[GEMM_BK][GEMM_BM];  // [k][m]
    __shared__ float Ws[GEMM_BK][GEMM_BN];  // [k][n]

    const int t = threadIdx.x;
    const int row0 = blockIdx.x * GEMM_BM;
    const int col0 = blockIdx.y * GEMM_BN;

    const int tm = (t & 15) * 4;
    const int tn = (t >> 4) * 4;

    float acc[4][4] = {};

    const int lr = t >> 3;       // 0..31
    const int lk = (t & 7) * 4;  // 0,4,...,28

    for (int k0 = 0; k0 < K; k0 += GEMM_BK) {
        #pragma unroll
        for (int pass = 0; pass < 2; ++pass) {
            int r = lr + pass * 32;
            const float4 v = *(const float4*)(A + (size_t)(row0 + r) * K + k0 + lk);
            As[lk + 0][r] = v.x; As[lk + 1][r] = v.y;
            As[lk + 2][r] = v.z; As[lk + 3][r] = v.w;
        }
        #pragma unroll
        for (int pass = 0; pass < 2; ++pass) {
            int n = lr + pass * 32;
            const float4 v = *(const float4*)(W + (size_t)(col0 + n) * K + k0 + lk);
            Ws[lk + 0][n] = v.x; Ws[lk + 1][n] = v.y;
            Ws[lk + 2][n] = v.z; Ws[lk + 3][n] = v.w;
        }
        __syncthreads();

        #pragma unroll
        for (int k = 0; k < GEMM_BK; ++k) {
            const float4 a = *(const float4*)&As[k][tm];
            const float4 w = *(const float4*)&Ws[k][tn];
            acc[0][0] += a.x * w.x; acc[0][1] += a.x * w.y; acc[0][2] += a.x * w.z; acc[0][3] += a.x * w.w;
            acc[1][0] += a.y * w.x; acc[1][1] += a.y * w.y; acc[1][2] += a.y * w.z; acc[1][3] += a.y * w.w;
            acc[2][0] += a.z * w.x; acc[2][1] += a.z * w.y; acc[2][2] += a.z * w.z; acc[2][3] += a.z * w.w;
            acc[3][0] += a.w * w.x; acc[3][1] += a.w * w.y; acc[3][2] += a.w * w.z; acc[3][3] += a.w * w.w;
        }
        __syncthreads();
    }

    float scl[4];
    #pragma unroll
    for (int i = 0; i < 4; ++i)
        scl[i] = HAS_RS ? (1.0f / deg[row0 + tm + i]) : 1.0f;

    float bb[4];
    #pragma unroll
    for (int j = 0; j < 4; ++j) bb[j] = bias[col0 + tn + j];

    #pragma unroll
    for (int i = 0; i < 4; ++i) {
        float4 v;
        v.x = acc[i][0] * scl[i] + bb[0];
        v.y = acc[i][1] * scl[i] + bb[1];
        v.z = acc[i][2] * scl[i] + bb[2];
        v.w = acc[i][3] * scl[i] + bb[3];
        if (RELU) {
            v.x = fmaxf(v.x, 0.0f); v.y = fmaxf(v.y, 0.0f);
            v.z = fmaxf(v.z, 0.0f); v.w = fmaxf(v.w, 0.0f);
        }
        *(float4*)(C + (size_t)(row0 + tm + i) * N + col0 + tn) = v;
    }
}

// ---------------------------------------------------------------------------
extern "C" void kernel_launch(void* const* d_in, const int* in_sizes, int n_in,
                              void* d_out, int out_size, void* d_ws, size_t ws_size,
                              hipStream_t stream) {
    const float* x   = (const float*)d_in[0];
    const int* src0  = (const int*)d_in[1];
    const int* dst0  = (const int*)d_in[2];
    const int* src1  = (const int*)d_in[3];
    const int* dst1  = (const int*)d_in[4];
    const float* W1  = (const float*)d_in[5];
    const float* b1  = (const float*)d_in[6];
    const float* W2  = (const float*)d_in[7];
    const float* b2  = (const float*)d_in[8];
    const float* Wh  = (const float*)d_in[9];
    const float* bh  = (const float*)d_in[10];

    const int E0 = in_sizes[1];
    const int E1 = in_sizes[3];
    const int IN = 128, HID = 256, OUT = 256, PHEAD = 64;
    const int ND0 = 131072, ND1 = 8192;

    float* ws = (float*)d_ws;
    float* neigh0 = ws;                          // ND0*IN  = 16,777,216 f (64 MB)
    float* deg0   = neigh0 + (size_t)ND0 * IN;   // ND0
    float* h1     = deg0 + ND0;                  // ND0*HID = 33,554,432 f (128 MB)
    float* out    = (float*)d_out;               // ND1*PHEAD

    // CSR0 overlaid in h1 (h1 not written until gemm1; CSR0 dead by then)
    int* count0     = (int*)h1;
    int* row_start0 = count0 + ND0;
    int* cursor0    = row_start0 + ND0;
    int* edge_src0  = cursor0 + ND0;             // E0 ints
    int* bsum0      = edge_src0 + E0;            // 256
    int* boff0      = bsum0 + 256;               // 256

    // layer-2 buffers overlaid in neigh0 (dead after gemm1)
    float* neigh1 = neigh0;                      // ND1*HID = 2,097,152 f
    float* deg1   = neigh1 + (size_t)ND1 * HID;  // ND1
    float* h2     = deg1 + ND1;                  // ND1*OUT = 2,097,152 f
    int* count1     = (int*)(h2 + (size_t)ND1 * OUT);
    int* row_start1 = count1 + ND1;
    int* cursor1    = row_start1 + ND1;
    int* edge_src1  = cursor1 + ND1;             // E1 ints
    int* bsum1      = edge_src1 + E1;            // 256
    int* boff1      = bsum1 + 256;               // 256

    // ---- layer 0: CSR build + gather aggregate ----
    hipMemsetAsync(count0, 0, ND0 * sizeof(int), stream);
    hist_kernel<<<E0 / 256, 256, 0, stream>>>(dst0, count0, E0);
    block_sum_kernel<<<ND0 / 1024, 256, 0, stream>>>(count0, bsum0);
    scan_small_kernel<<<1, 256, 0, stream>>>(bsum0, boff0, ND0 / 1024);
    scan_final_kernel<<<ND0 / 1024, 256, 0, stream>>>(count0, boff0, row_start0, cursor0);
    fill_kernel<<<E0 / 256, 256, 0, stream>>>(src0, dst0, cursor0, edge_src0, E0);
    agg_kernel<2><<<ND0 / 4, 256, 0, stream>>>(x, x, row_start0, count0, edge_src0,
                                               neigh0, deg0, ND0);
    {
        dim3 g(ND0 / GEMM_BM, HID / GEMM_BN);
        gemm_kernel<true, true><<<g, 256, 0, stream>>>(neigh0, deg0, W1, b1, h1, ND0, HID, IN);
    }

    // ---- layer 1 ----
    hipMemsetAsync(count1, 0, ND1 * sizeof(int), stream);
    hist_kernel<<<E1 / 256, 256, 0, stream>>>(dst1, count1, E1);
    block_sum_kernel<<<ND1 / 1024, 256, 0, stream>>>(count1, bsum1);
    scan_small_kernel<<<1, 256, 0, stream>>>(bsum1, boff1, ND1 / 1024);
    scan_final_kernel<<<ND1 / 1024, 256, 0, stream>>>(count1, boff1, row_start1, cursor1);
    fill_kernel<<<E1 / 256, 256, 0, stream>>>(src1, dst1, cursor1, edge_src1, E1);
    agg_kernel<4><<<ND1 / 4, 256, 0, stream>>>(h1, h1, row_start1, count1, edge_src1,
                                               neigh1, deg1, ND1);
    {
        dim3 g(ND1 / GEMM_BM, OUT / GEMM_BN);
        gemm_kernel<true, true><<<g, 256, 0, stream>>>(neigh1, deg1, W2, b2, h2, ND1, OUT, HID);
    }

    // ---- head ----
    {
        dim3 g(ND1 / GEMM_BM, PHEAD / GEMM_BN);
        gemm_kernel<false, false><<<g, 256, 0, stream>>>(h2, nullptr, Wh, bh, out, ND1, PHEAD, OUT);
    }
}

// Round 3
// 1260.332 us; speedup vs baseline: 3.8526x; 1.1115x over previous
//
#include <hip/hip_runtime.h>

// GCNStoModel_MultiHead: 2-layer GraphSAGE-GCN + linear head.
// IN=128, HID=256, OUT=256, PHEAD=64
// N0=1048576, E0=2097152, ND0=131072, E1=131072, ND1=8192, task_index=0.
//
// R1: CSR build + gather aggregation (no float atomics).
// R2: agg latency fix — cooperative edge-index load + __shfl broadcast +
//     8-deep software-pipelined gathers (was a 1-deep dependent chain).

#define GEMM_BM 64
#define GEMM_BN 64
#define GEMM_BK 32

// ---------------------------------------------------------------------------
// CSR build step 1: count[d] = #edges with dst==d   (count pre-zeroed)
__global__ __launch_bounds__(256) void hist_kernel(const int* __restrict__ dst,
                                                   int* __restrict__ count, int E) {
    int e = blockIdx.x * 256 + threadIdx.x;
    if (e >= E) return;
    atomicAdd(&count[dst[e]], 1);
}

// CSR build step 2a: per-block (1024-elem) sums
__global__ __launch_bounds__(256) void block_sum_kernel(const int* __restrict__ count,
                                                        int* __restrict__ bsum) {
    __shared__ int sdata[256];
    int t = threadIdx.x;
    int i = blockIdx.x * 1024 + t * 4;
    int s = count[i] + count[i + 1] + count[i + 2] + count[i + 3];
    sdata[t] = s;
    __syncthreads();
    for (int off = 128; off > 0; off >>= 1) {
        if (t < off) sdata[t] += sdata[t + off];
        __syncthreads();
    }
    if (t == 0) bsum[blockIdx.x] = sdata[0];
}

// CSR build step 2b: exclusive scan of nb block sums (nb <= 256), one block
__global__ __launch_bounds__(256) void scan_small_kernel(const int* __restrict__ bsum,
                                                         int* __restrict__ boff, int nb) {
    __shared__ int sdata[256];
    int t = threadIdx.x;
    int v = (t < nb) ? bsum[t] : 0;
    sdata[t] = v;
    __syncthreads();
    int val = v;
    for (int off = 1; off < 256; off <<= 1) {
        int x = (t >= off) ? sdata[t - off] : 0;
        __syncthreads();
        val += x;
        sdata[t] = val;
        __syncthreads();
    }
    if (t < nb) boff[t] = val - v;  // exclusive
}

// CSR build step 2c: final exclusive scan -> row_start (and cursor copy)
__global__ __launch_bounds__(256) void scan_final_kernel(const int* __restrict__ count,
                                                         const int* __restrict__ boff,
                                                         int* __restrict__ row_start,
                                                         int* __restrict__ cursor) {
    __shared__ int sdata[256];
    int t = threadIdx.x;
    int base_i = blockIdx.x * 1024 + t * 4;
    int c0 = count[base_i], c1 = count[base_i + 1], c2 = count[base_i + 2], c3 = count[base_i + 3];
    int local = c0 + c1 + c2 + c3;
    sdata[t] = local;
    __syncthreads();
    int val = local;
    for (int off = 1; off < 256; off <<= 1) {
        int x = (t >= off) ? sdata[t - off] : 0;
        __syncthreads();
        val += x;
        sdata[t] = val;
        __syncthreads();
    }
    int base = boff[blockIdx.x] + (val - local);  // exclusive prefix
    int r0 = base, r1 = r0 + c0, r2 = r1 + c1, r3 = r2 + c2;
    row_start[base_i] = r0; row_start[base_i + 1] = r1;
    row_start[base_i + 2] = r2; row_start[base_i + 3] = r3;
    cursor[base_i] = r0; cursor[base_i + 1] = r1;
    cursor[base_i + 2] = r2; cursor[base_i + 3] = r3;
}

// CSR build step 3: bucket edges by dst
__global__ __launch_bounds__(256) void fill_kernel(const int* __restrict__ src,
                                                   const int* __restrict__ dst,
                                                   int* __restrict__ cursor,
                                                   int* __restrict__ edge_src, int E) {
    int e = blockIdx.x * 256 + threadIdx.x;
    if (e >= E) return;
    int d = dst[e];
    int p = atomicAdd(&cursor[d], 1);
    edge_src[p] = src[e];
}

// ---------------------------------------------------------------------------
// gather aggregation: one wave per dst row; row held in registers (RF floats
// per lane, K = 64*RF). neigh[d] = selff[d] + sum_{e in row d} feat[src[e]];
// deg[d] = count[d] + 1.
// R2: edge indices loaded cooperatively (1/lane) + __shfl broadcast; feature
// gathers pipelined 8-deep with masked (×0) padding so the pipeline stays
// full even at mean degree 16.
template<int RF> struct VecSel;
template<> struct VecSel<2> { using V = float2; };
template<> struct VecSel<4> { using V = float4; };

template<int RF>
__global__ __launch_bounds__(256) void agg_kernel(const float* __restrict__ feat,
                                                  const float* __restrict__ selff,
                                                  const int* __restrict__ row_start,
                                                  const int* __restrict__ count,
                                                  const int* __restrict__ edge_src,
                                                  float* __restrict__ neigh,
                                                  float* __restrict__ deg, int ND) {
    using V = typename VecSel<RF>::V;
    int w = (blockIdx.x * 256 + threadIdx.x) >> 6;  // wave id == dst row
    int lane = threadIdx.x & 63;
    if (w >= ND) return;
    const int K = 64 * RF;
    size_t lo = (size_t)w * K + (size_t)lane * RF;
    V acc = *(const V*)(selff + lo);
    const int rs = row_start[w];
    const int cnt = count[w];

    for (int base = 0; base < cnt; base += 64) {
        const int rem = min(cnt - base, 64);                 // >= 1
        // cooperative, coalesced index load (clamped; mask fixes validity)
        const int idx = edge_src[rs + base + min(lane, rem - 1)];

        for (int jj = 0; jj < rem; jj += 8) {
            int s[8];
            float m[8];
            #pragma unroll
            for (int k = 0; k < 8; ++k) {
                int j = jj + k;
                s[k] = __shfl(idx, min(j, rem - 1));
                m[k] = (j < rem) ? 1.0f : 0.0f;
            }
            V v[8];
            #pragma unroll
            for (int k = 0; k < 8; ++k)
                v[k] = *(const V*)(feat + (size_t)s[k] * K + (size_t)lane * RF);
            #pragma unroll
            for (int k = 0; k < 8; ++k) {
                acc.x += v[k].x * m[k];
                acc.y += v[k].y * m[k];
                if constexpr (RF == 4) {
                    acc.z += v[k].z * m[k];
                    acc.w += v[k].w * m[k];
                }
            }
        }
    }
    *(V*)(neigh + lo) = acc;
    if (lane == 0) deg[w] = (float)(cnt + 1);
}

// ---------------------------------------------------------------------------
// C[M,N] = act( (A * rowscale) @ W^T + b ), fp32, 64x64x32 tiles, 4x4/thread.
template<bool RELU, bool HAS_RS>
__global__ __launch_bounds__(256) void gemm_kernel(const float* __restrict__ A,    // M x K
                                                   const float* __restrict__ deg,  // M or null
                                                   const float* __restrict__ W,    // N x K
                                                   const float* __restrict__ bias, // N
                                                   float* __restrict__ C,          // M x N
                                                   int M, int N, int K) {
    __shared__ float As[GEMM_BK][GEMM_BM];  // [k][m]
    __shared__ float Ws[GEMM_BK][GEMM_BN];  // [k][n]

    const int t = threadIdx.x;
    const int row0 = blockIdx.x * GEMM_BM;
    const int col0 = blockIdx.y * GEMM_BN;

    const int tm = (t & 15) * 4;
    const int tn = (t >> 4) * 4;

    float acc[4][4] = {};

    const int lr = t >> 3;       // 0..31
    const int lk = (t & 7) * 4;  // 0,4,...,28

    for (int k0 = 0; k0 < K; k0 += GEMM_BK) {
        #pragma unroll
        for (int pass = 0; pass < 2; ++pass) {
            int r = lr + pass * 32;
            const float4 v = *(const float4*)(A + (size_t)(row0 + r) * K + k0 + lk);
            As[lk + 0][r] = v.x; As[lk + 1][r] = v.y;
            As[lk + 2][r] = v.z; As[lk + 3][r] = v.w;
        }
        #pragma unroll
        for (int pass = 0; pass < 2; ++pass) {
            int n = lr + pass * 32;
            const float4 v = *(const float4*)(W + (size_t)(col0 + n) * K + k0 + lk);
            Ws[lk + 0][n] = v.x; Ws[lk + 1][n] = v.y;
            Ws[lk + 2][n] = v.z; Ws[lk + 3][n] = v.w;
        }
        __syncthreads();

        #pragma unroll
        for (int k = 0; k < GEMM_BK; ++k) {
            const float4 a = *(const float4*)&As[k][tm];
            const float4 w = *(const float4*)&Ws[k][tn];
            acc[0][0] += a.x * w.x; acc[0][1] += a.x * w.y; acc[0][2] += a.x * w.z; acc[0][3] += a.x * w.w;
            acc[1][0] += a.y * w.x; acc[1][1] += a.y * w.y; acc[1][2] += a.y * w.z; acc[1][3] += a.y * w.w;
            acc[2][0] += a.z * w.x; acc[2][1] += a.z * w.y; acc[2][2] += a.z * w.z; acc[2][3] += a.z * w.w;
            acc[3][0] += a.w * w.x; acc[3][1] += a.w * w.y; acc[3][2] += a.w * w.z; acc[3][3] += a.w * w.w;
        }
        __syncthreads();
    }

    float scl[4];
    #pragma unroll
    for (int i = 0; i < 4; ++i)
        scl[i] = HAS_RS ? (1.0f / deg[row0 + tm + i]) : 1.0f;

    float bb[4];
    #pragma unroll
    for (int j = 0; j < 4; ++j) bb[j] = bias[col0 + tn + j];

    #pragma unroll
    for (int i = 0; i < 4; ++i) {
        float4 v;
        v.x = acc[i][0] * scl[i] + bb[0];
        v.y = acc[i][1] * scl[i] + bb[1];
        v.z = acc[i][2] * scl[i] + bb[2];
        v.w = acc[i][3] * scl[i] + bb[3];
        if (RELU) {
            v.x = fmaxf(v.x, 0.0f); v.y = fmaxf(v.y, 0.0f);
            v.z = fmaxf(v.z, 0.0f); v.w = fmaxf(v.w, 0.0f);
        }
        *(float4*)(C + (size_t)(row0 + tm + i) * N + col0 + tn) = v;
    }
}

// ---------------------------------------------------------------------------
extern "C" void kernel_launch(void* const* d_in, const int* in_sizes, int n_in,
                              void* d_out, int out_size, void* d_ws, size_t ws_size,
                              hipStream_t stream) {
    const float* x   = (const float*)d_in[0];
    const int* src0  = (const int*)d_in[1];
    const int* dst0  = (const int*)d_in[2];
    const int* src1  = (const int*)d_in[3];
    const int* dst1  = (const int*)d_in[4];
    const float* W1  = (const float*)d_in[5];
    const float* b1  = (const float*)d_in[6];
    const float* W2  = (const float*)d_in[7];
    const float* b2  = (const float*)d_in[8];
    const float* Wh  = (const float*)d_in[9];
    const float* bh  = (const float*)d_in[10];

    const int E0 = in_sizes[1];
    const int E1 = in_sizes[3];
    const int IN = 128, HID = 256, OUT = 256, PHEAD = 64;
    const int ND0 = 131072, ND1 = 8192;

    float* ws = (float*)d_ws;
    float* neigh0 = ws;                          // ND0*IN  = 16,777,216 f (64 MB)
    float* deg0   = neigh0 + (size_t)ND0 * IN;   // ND0
    float* h1     = deg0 + ND0;                  // ND0*HID = 33,554,432 f (128 MB)
    float* out    = (float*)d_out;               // ND1*PHEAD

    // CSR0 overlaid in h1 (h1 not written until gemm1; CSR0 dead by then)
    int* count0     = (int*)h1;
    int* row_start0 = count0 + ND0;
    int* cursor0    = row_start0 + ND0;
    int* edge_src0  = cursor0 + ND0;             // E0 ints
    int* bsum0      = edge_src0 + E0;            // 256
    int* boff0      = bsum0 + 256;               // 256

    // layer-2 buffers overlaid in neigh0 (dead after gemm1)
    float* neigh1 = neigh0;                      // ND1*HID = 2,097,152 f
    float* deg1   = neigh1 + (size_t)ND1 * HID;  // ND1
    float* h2     = deg1 + ND1;                  // ND1*OUT = 2,097,152 f
    int* count1     = (int*)(h2 + (size_t)ND1 * OUT);
    int* row_start1 = count1 + ND1;
    int* cursor1    = row_start1 + ND1;
    int* edge_src1  = cursor1 + ND1;             // E1 ints
    int* bsum1      = edge_src1 + E1;            // 256
    int* boff1      = bsum1 + 256;               // 256

    // ---- layer 0: CSR build + gather aggregate ----
    hipMemsetAsync(count0, 0, ND0 * sizeof(int), stream);
    hist_kernel<<<E0 / 256, 256, 0, stream>>>(dst0, count0, E0);
    block_sum_kernel<<<ND0 / 1024, 256, 0, stream>>>(count0, bsum0);
    scan_small_kernel<<<1, 256, 0, stream>>>(bsum0, boff0, ND0 / 1024);
    scan_final_kernel<<<ND0 / 1024, 256, 0, stream>>>(count0, boff0, row_start0, cursor0);
    fill_kernel<<<E0 / 256, 256, 0, stream>>>(src0, dst0, cursor0, edge_src0, E0);
    agg_kernel<2><<<ND0 / 4, 256, 0, stream>>>(x, x, row_start0, count0, edge_src0,
                                               neigh0, deg0, ND0);
    {
        dim3 g(ND0 / GEMM_BM, HID / GEMM_BN);
        gemm_kernel<true, true><<<g, 256, 0, stream>>>(neigh0, deg0, W1, b1, h1, ND0, HID, IN);
    }

    // ---- layer 1 ----
    hipMemsetAsync(count1, 0, ND1 * sizeof(int), stream);
    hist_kernel<<<E1 / 256, 256, 0, stream>>>(dst1, count1, E1);
    block_sum_kernel<<<ND1 / 1024, 256, 0, stream>>>(count1, bsum1);
    scan_small_kernel<<<1, 256, 0, stream>>>(bsum1, boff1, ND1 / 1024);
    scan_final_kernel<<<ND1 / 1024, 256, 0, stream>>>(count1, boff1, row_start1, cursor1);
    fill_kernel<<<E1 / 256, 256, 0, stream>>>(src1, dst1, cursor1, edge_src1, E1);
    agg_kernel<4><<<ND1 / 4, 256, 0, stream>>>(h1, h1, row_start1, count1, edge_src1,
                                               neigh1, deg1, ND1);
    {
        dim3 g(ND1 / GEMM_BM, OUT / GEMM_BN);
        gemm_kernel<true, true><<<g, 256, 0, stream>>>(neigh1, deg1, W2, b2, h2, ND1, OUT, HID);
    }

    // ---- head ----
    {
        dim3 g(ND1 / GEMM_BM, PHEAD / GEMM_BN);
        gemm_kernel<false, false><<<g, 256, 0, stream>>>(h2, nullptr, Wh, bh, out, ND1, PHEAD, OUT);
    }
}